// Round 1
// baseline (2035.800 us; speedup 1.0000x reference)
//
#include <hip/hip_runtime.h>
#include <math.h>

#define TWO_PI_F 6.283185307179586476925286766559f

// ws layout (float offsets)
#define WT0_OFF 0            // [160][256]  layer0 weights, K-major
#define WT1_OFF 40960        // [384][256]  layer1 weights, K-major
#define WMT_OFF 139264       // [296][512]  W_mod transposed (for pc precompute)
#define PC_OFF  290816       // [1024][512] per-b modulation constants
// total 815104 floats = 3,260,416 bytes of d_ws

__device__ __forceinline__ void fma4(float4& c, float a, const float4& w) {
  c.x = fmaf(a, w.x, c.x);
  c.y = fmaf(a, w.y, c.y);
  c.z = fmaf(a, w.z, c.z);
  c.w = fmaf(a, w.w, c.w);
}

// ---------------- kernel A2: pack transposed weight panels ----------------
__global__ void pack_weights_k(const float* __restrict__ W0,
                               const float* __restrict__ W1,
                               const float* __restrict__ W_mod,
                               float* __restrict__ WT0,
                               float* __restrict__ WT1,
                               float* __restrict__ WmT) {
  int i0 = blockIdx.x * blockDim.x + threadIdx.x;
  int stride = gridDim.x * blockDim.x;
  // WT0[k][n]: k<17 -> W0[n][k]; 17..31 -> 0; 32..159 -> W_mod[n][128+(k-32)]
  for (int idx = i0; idx < 160 * 256; idx += stride) {
    int k = idx >> 8, n = idx & 255;
    float v = 0.0f;
    if (k < 17) v = W0[n * 17 + k];
    else if (k >= 32) v = W_mod[n * 296 + 128 + (k - 32)];
    WT0[idx] = v;
  }
  // WT1[k][n]: k<256 -> W1[n][k]; 256..383 -> W_mod[256+n][128+(k-256)]
  for (int idx = i0; idx < 384 * 256; idx += stride) {
    int k = idx >> 8, n = idx & 255;
    WT1[idx] = (k < 256) ? W1[n * 256 + k]
                         : W_mod[(256 + n) * 296 + 128 + (k - 256)];
  }
  // WmT[c][m] = W_mod[m][c]
  for (int idx = i0; idx < 296 * 512; idx += stride) {
    int c = idx >> 9, m = idx & 511;
    WmT[idx] = W_mod[m * 296 + c];
  }
}

// ---------------- kernel A1: static encoder + per-b modulation consts ----------------
__global__ void precompute_pc_k(const float* __restrict__ code,
                                const float* __restrict__ x_statics,
                                const int* __restrict__ dir_idx,
                                const float* __restrict__ WmT,
                                const float* __restrict__ b_mod,
                                const float* __restrict__ b0,
                                const float* __restrict__ b1,
                                const float* __restrict__ Bmat,
                                const float* __restrict__ Ws1,
                                const float* __restrict__ bs1,
                                const float* __restrict__ Ws2,
                                const float* __restrict__ bs2,
                                const float* __restrict__ dir_emb,
                                float* __restrict__ pc) {
  int b = blockIdx.x, t = threadIdx.x;  // 512 threads
  __shared__ float feats[32];
  __shared__ float h[64];
  __shared__ float se[40];
  __shared__ float cd[128];
  if (t < 16) {
    float p = TWO_PI_F * (x_statics[2 * b] * Bmat[t] + x_statics[2 * b + 1] * Bmat[16 + t]);
    feats[t] = sinf(p);
    feats[16 + t] = cosf(p);
  }
  if (t >= 128 && t < 256) cd[t - 128] = code[b * 128 + (t - 128)];
  __syncthreads();
  if (t < 64) {
    float a = bs1[t];
#pragma unroll
    for (int c = 0; c < 32; ++c) a = fmaf(feats[c], Ws1[t * 32 + c], a);
    h[t] = 0.5f * a * (1.0f + erff(a * 0.70710678118654752440f));  // exact GELU
  }
  __syncthreads();
  if (t < 32) {
    float a = bs2[t];
#pragma unroll
    for (int c = 0; c < 64; ++c) a = fmaf(h[c], Ws2[t * 64 + c], a);
    se[t] = a;
  } else if (t < 40) {
    se[t] = dir_emb[dir_idx[b] * 8 + (t - 32)];
  }
  __syncthreads();
  // pc[b][m] = b_mod[m] + (m<256? b0[m] : b1[m-256]) + code.Wcode + se.Wstatic
  float a = b_mod[t] + ((t < 256) ? b0[t] : b1[t - 256]);
  for (int c = 0; c < 128; ++c) a = fmaf(cd[c], WmT[c * 512 + t], a);
#pragma unroll
  for (int c = 0; c < 40; ++c) a = fmaf(se[c], WmT[(256 + c) * 512 + t], a);
  pc[b * 512 + t] = a;
}

// ---------------- kernel B: fused FiLM MLP main ----------------
// grid = 1024 (one block per b), block = 512 threads (8 waves).
// Each block loops 16 tiles of TM=32 rows. Per tile:
//   u[32][160]  = [pos(17) | 0 pad | hs(128)]
//   GEMM0 (K=160,N=256) -> relu(+pc0) -> x0s[32][256]
//   GEMM1 (K=384: x0s then hs, N=256) -> relu(+pc1) -> dot Wo -> out
__global__ __launch_bounds__(512, 4) void film_main(
    const float* __restrict__ coords, const float* __restrict__ hs,
    const float* __restrict__ pc, const float* __restrict__ WT0,
    const float* __restrict__ WT1, const float* __restrict__ Wo,
    const float* __restrict__ bo, float* __restrict__ out) {
  const int b = blockIdx.x;
  const int tid = threadIdx.x;
  const int wave = tid >> 6;  // 0..7 -> rows wave*4..wave*4+3
  const int lane = tid & 63;  // cols lane*4..lane*4+3

  __shared__ float u[32][160];
  __shared__ float x0s[32][256];
  __shared__ float wc[16 * 256];
  __shared__ float pcs[512];

  pcs[tid] = pc[b * 512 + tid];
  const float4 wo4 = ((const float4*)Wo)[lane];
  const float bo0 = bo[0];

  for (int tile = 0; tile < 16; ++tile) {
    const int t0 = tile * 32;
    __syncthreads();  // protect u/x0s from previous tile's readers

    // ---- fill pos (+zero pad) ----
    if (tid < 32) {
      int r = tid;
      float c = coords[b * 512 + t0 + r];
      u[r][0] = c;
#pragma unroll
      for (int f = 0; f < 8; ++f) {
        float wv = c * (1.25f * (float)f);
        u[r][1 + f] = sinf(wv);
        u[r][9 + f] = cosf(wv);
      }
#pragma unroll
      for (int z = 17; z < 32; ++z) u[r][z] = 0.0f;
    }
    // ---- fill hs into u[:,32:160] ----
    {
      const float4* hsrc = (const float4*)(hs + (size_t)(b * 512 + t0) * 128);
#pragma unroll
      for (int i = 0; i < 2; ++i) {
        int f = tid + i * 512;  // float4 id, 32 per row
        int r = f >> 5, c4 = f & 31;
        float4 val = hsrc[f];
        *(float4*)&u[r][32 + c4 * 4] = val;
      }
    }
    __syncthreads();

    // ---------------- GEMM0: K=160 ----------------
    float4 acc[4];
#pragma unroll
    for (int i = 0; i < 4; ++i) acc[i] = make_float4(0.f, 0.f, 0.f, 0.f);

    for (int kc = 0; kc < 160; kc += 16) {
      __syncthreads();  // previous chunk consumed
      const float4* src = (const float4*)(WT0 + kc * 256);
      ((float4*)wc)[tid] = src[tid];
      ((float4*)wc)[tid + 512] = src[tid + 512];
      __syncthreads();
#pragma unroll
      for (int k = 0; k < 16; ++k) {
        float4 w = *(const float4*)&wc[k * 256 + lane * 4];
        float a0 = u[wave * 4 + 0][kc + k];
        float a1 = u[wave * 4 + 1][kc + k];
        float a2 = u[wave * 4 + 2][kc + k];
        float a3 = u[wave * 4 + 3][kc + k];
        fma4(acc[0], a0, w);
        fma4(acc[1], a1, w);
        fma4(acc[2], a2, w);
        fma4(acc[3], a3, w);
      }
    }
    // epilogue 0: relu(+pc0) -> x0s
    __syncthreads();
#pragma unroll
    for (int i = 0; i < 4; ++i) {
      float4 p;
      p.x = fmaxf(acc[i].x + pcs[lane * 4 + 0], 0.f);
      p.y = fmaxf(acc[i].y + pcs[lane * 4 + 1], 0.f);
      p.z = fmaxf(acc[i].z + pcs[lane * 4 + 2], 0.f);
      p.w = fmaxf(acc[i].w + pcs[lane * 4 + 3], 0.f);
      *(float4*)&x0s[wave * 4 + i][lane * 4] = p;
    }

    // ---------------- GEMM1: K=384 (x0 256 + hs 128) ----------------
#pragma unroll
    for (int i = 0; i < 4; ++i) acc[i] = make_float4(0.f, 0.f, 0.f, 0.f);

    for (int kc = 0; kc < 256; kc += 16) {
      __syncthreads();
      const float4* src = (const float4*)(WT1 + kc * 256);
      ((float4*)wc)[tid] = src[tid];
      ((float4*)wc)[tid + 512] = src[tid + 512];
      __syncthreads();
#pragma unroll
      for (int k = 0; k < 16; ++k) {
        float4 w = *(const float4*)&wc[k * 256 + lane * 4];
        float a0 = x0s[wave * 4 + 0][kc + k];
        float a1 = x0s[wave * 4 + 1][kc + k];
        float a2 = x0s[wave * 4 + 2][kc + k];
        float a3 = x0s[wave * 4 + 3][kc + k];
        fma4(acc[0], a0, w);
        fma4(acc[1], a1, w);
        fma4(acc[2], a2, w);
        fma4(acc[3], a3, w);
      }
    }
    for (int kc = 0; kc < 128; kc += 16) {
      __syncthreads();
      const float4* src = (const float4*)(WT1 + (256 + kc) * 256);
      ((float4*)wc)[tid] = src[tid];
      ((float4*)wc)[tid + 512] = src[tid + 512];
      __syncthreads();
#pragma unroll
      for (int k = 0; k < 16; ++k) {
        float4 w = *(const float4*)&wc[k * 256 + lane * 4];
        float a0 = u[wave * 4 + 0][32 + kc + k];
        float a1 = u[wave * 4 + 1][32 + kc + k];
        float a2 = u[wave * 4 + 2][32 + kc + k];
        float a3 = u[wave * 4 + 3][32 + kc + k];
        fma4(acc[0], a0, w);
        fma4(acc[1], a1, w);
        fma4(acc[2], a2, w);
        fma4(acc[3], a3, w);
      }
    }

    // epilogue 1: relu(+pc1) dot Wo, wave-wide butterfly reduce, write out
    float po[4];
#pragma unroll
    for (int i = 0; i < 4; ++i) {
      float s;
      s = fmaxf(acc[i].x + pcs[256 + lane * 4 + 0], 0.f) * wo4.x;
      s += fmaxf(acc[i].y + pcs[256 + lane * 4 + 1], 0.f) * wo4.y;
      s += fmaxf(acc[i].z + pcs[256 + lane * 4 + 2], 0.f) * wo4.z;
      s += fmaxf(acc[i].w + pcs[256 + lane * 4 + 3], 0.f) * wo4.w;
      po[i] = s;
    }
#pragma unroll
    for (int off = 32; off > 0; off >>= 1) {
      po[0] += __shfl_xor(po[0], off);
      po[1] += __shfl_xor(po[1], off);
      po[2] += __shfl_xor(po[2], off);
      po[3] += __shfl_xor(po[3], off);
    }
    if (lane == 0) {
#pragma unroll
      for (int i = 0; i < 4; ++i) out[b * 512 + t0 + wave * 4 + i] = po[i] + bo0;
    }
  }
}

extern "C" void kernel_launch(void* const* d_in, const int* in_sizes, int n_in,
                              void* d_out, int out_size, void* d_ws, size_t ws_size,
                              hipStream_t stream) {
  (void)in_sizes; (void)n_in; (void)out_size; (void)ws_size;
  const float* coords    = (const float*)d_in[0];
  const float* code      = (const float*)d_in[1];
  const float* hs        = (const float*)d_in[2];
  const float* x_statics = (const float*)d_in[3];
  const int*   dir_idx   = (const int*)d_in[4];
  const float* W_mod     = (const float*)d_in[5];
  const float* b_mod     = (const float*)d_in[6];
  const float* W0        = (const float*)d_in[7];
  const float* b0        = (const float*)d_in[8];
  const float* W1        = (const float*)d_in[9];
  const float* b1        = (const float*)d_in[10];
  const float* Wo        = (const float*)d_in[11];
  const float* bo        = (const float*)d_in[12];
  const float* Bmat      = (const float*)d_in[13];
  const float* Ws1       = (const float*)d_in[14];
  const float* bs1       = (const float*)d_in[15];
  const float* Ws2       = (const float*)d_in[16];
  const float* bs2       = (const float*)d_in[17];
  const float* dir_emb   = (const float*)d_in[18];
  float* out = (float*)d_out;
  float* wsf = (float*)d_ws;

  float* WT0 = wsf + WT0_OFF;
  float* WT1 = wsf + WT1_OFF;
  float* WmT = wsf + WMT_OFF;
  float* pc  = wsf + PC_OFF;

  hipLaunchKernelGGL(pack_weights_k, dim3(512), dim3(256), 0, stream,
                     W0, W1, W_mod, WT0, WT1, WmT);
  hipLaunchKernelGGL(precompute_pc_k, dim3(1024), dim3(512), 0, stream,
                     code, x_statics, dir_idx, WmT, b_mod, b0, b1,
                     Bmat, Ws1, bs1, Ws2, bs2, dir_emb, pc);
  hipLaunchKernelGGL(film_main, dim3(1024), dim3(512), 0, stream,
                     coords, hs, pc, WT0, WT1, Wo, bo, out);
}

// Round 2
// 210.375 us; speedup vs baseline: 9.6770x; 9.6770x over previous
//
#include <hip/hip_runtime.h>
#include <math.h>

typedef unsigned short ushort_t;
typedef unsigned int uint_t;
typedef __bf16 bf16x8 __attribute__((ext_vector_type(8)));
typedef float f32x4 __attribute__((ext_vector_type(4)));

#define TWO_PI_F 6.283185307179586f

// ---- ws float-offset layout ----
#define WMT_OFF   0         // [296][512] f32 W_mod^T (for pc precompute)
#define PC_OFF    151552    // [1024][512] f32 per-b modulation constants
#define WT0P_OFF  675840    // 40960 ushort: GEMM0 B-frags [5 ks][16 nt][64 l][8 j]
#define WT1P_OFF  696320    // 98304 ushort: GEMM1 B-frags [12 ks][16 nt][64 l][8 j]
// total = 745472 floats = 2.98 MB

__device__ __forceinline__ ushort_t f2bf(float f) {
  unsigned int u = __float_as_uint(f);
  u += 0x7fffu + ((u >> 16) & 1u);
  return (ushort_t)(u >> 16);
}

// ---------------- pack: W_mod^T (f32) + MFMA B-fragment panels (bf16) ----------------
__global__ void pack_mfma_k(const float* __restrict__ W0,
                            const float* __restrict__ W1,
                            const float* __restrict__ W_mod,
                            float* __restrict__ WmT,
                            ushort_t* __restrict__ WT0p,
                            ushort_t* __restrict__ WT1p) {
  int i0 = blockIdx.x * blockDim.x + threadIdx.x;
  int stride = gridDim.x * blockDim.x;
  // WmT[c][m] = W_mod[m][c]
  for (int idx = i0; idx < 296 * 512; idx += stride) {
    int c = idx >> 9, m = idx & 511;
    WmT[idx] = W_mod[m * 296 + c];
  }
  // WT0p: B0[k][n], k = ks*32 + (l>>4)*8 + j ; n = nt*16 + (l&15)
  //   k<17: W0[n][k]; 17..31: 0 (pos pad); 32..159: W_mod[n][128+(k-32)]
  for (int e = i0; e < 40960; e += stride) {
    int j = e & 7, l = (e >> 3) & 63, nt = (e >> 9) & 15, ks = e >> 13;
    int k = ks * 32 + (l >> 4) * 8 + j;
    int n = nt * 16 + (l & 15);
    float v = 0.0f;
    if (k < 17) v = W0[n * 17 + k];
    else if (k >= 32) v = W_mod[n * 296 + 128 + (k - 32)];
    WT0p[e] = f2bf(v);
  }
  // WT1p: B1[k][n]: k<256 -> W1[n][k]; 256..383 -> W_mod[256+n][128+(k-256)]
  for (int e = i0; e < 98304; e += stride) {
    int j = e & 7, l = (e >> 3) & 63, nt = (e >> 9) & 15, ks = e >> 13;
    int k = ks * 32 + (l >> 4) * 8 + j;
    int n = nt * 16 + (l & 15);
    float v = (k < 256) ? W1[n * 256 + k]
                        : W_mod[(256 + n) * 296 + 128 + (k - 256)];
    WT1p[e] = f2bf(v);
  }
}

// ---------------- static encoder + per-b modulation consts (unchanged, verified R1) ----------------
__global__ void precompute_pc_k(const float* __restrict__ code,
                                const float* __restrict__ x_statics,
                                const int* __restrict__ dir_idx,
                                const float* __restrict__ WmT,
                                const float* __restrict__ b_mod,
                                const float* __restrict__ b0,
                                const float* __restrict__ b1,
                                const float* __restrict__ Bmat,
                                const float* __restrict__ Ws1,
                                const float* __restrict__ bs1,
                                const float* __restrict__ Ws2,
                                const float* __restrict__ bs2,
                                const float* __restrict__ dir_emb,
                                float* __restrict__ pc) {
  int b = blockIdx.x, t = threadIdx.x;  // 512 threads
  __shared__ float feats[32];
  __shared__ float h[64];
  __shared__ float se[40];
  __shared__ float cd[128];
  if (t < 16) {
    float p = TWO_PI_F * (x_statics[2 * b] * Bmat[t] + x_statics[2 * b + 1] * Bmat[16 + t]);
    feats[t] = sinf(p);
    feats[16 + t] = cosf(p);
  }
  if (t >= 128 && t < 256) cd[t - 128] = code[b * 128 + (t - 128)];
  __syncthreads();
  if (t < 64) {
    float a = bs1[t];
#pragma unroll
    for (int c = 0; c < 32; ++c) a = fmaf(feats[c], Ws1[t * 32 + c], a);
    h[t] = 0.5f * a * (1.0f + erff(a * 0.70710678118654752440f));
  }
  __syncthreads();
  if (t < 32) {
    float a = bs2[t];
#pragma unroll
    for (int c = 0; c < 64; ++c) a = fmaf(h[c], Ws2[t * 64 + c], a);
    se[t] = a;
  } else if (t < 40) {
    se[t] = dir_emb[dir_idx[b] * 8 + (t - 32)];
  }
  __syncthreads();
  float a = b_mod[t] + ((t < 256) ? b0[t] : b1[t - 256]);
  for (int c = 0; c < 128; ++c) a = fmaf(cd[c], WmT[c * 512 + t], a);
#pragma unroll
  for (int c = 0; c < 40; ++c) a = fmaf(se[c], WmT[(256 + c) * 512 + t], a);
  pc[b * 512 + t] = a;
}

// ---------------- main: MFMA FiLM MLP ----------------
// grid = 8192 (64 rows each), block = 256 threads = 4 waves.
// Per wave: RA=4 M-tiles (all 64 rows) x RB=4 N-tiles (64 of 256 cols).
// rowbuf per row (768B): bytes [0,512) = x0 (256 bf16), [512,768) = hs (128 bf16),
// XOR-swizzled with ((row&7)<<4). B-frags stream global->regs (L2-hot, 272KB).
__global__ __launch_bounds__(256, 3) void film_mfma(
    const float* __restrict__ coords, const float* __restrict__ hs,
    const float* __restrict__ pc, const ushort_t* __restrict__ WT0p,
    const ushort_t* __restrict__ WT1p, const float* __restrict__ Wo,
    const float* __restrict__ bo, float* __restrict__ out) {
  __shared__ uint4 rowbuf4[49152 / 16];
  __shared__ float pcs[512];
  __shared__ float psum[4][64];
  char* rowbuf = (char*)rowbuf4;

  const int tid = threadIdx.x;
  const int wv = tid >> 6;
  const int l = tid & 63;
  const int l4 = l & 15;
  const int hi4 = l >> 4;
  const size_t row0 = (size_t)blockIdx.x * 64;
  const int b = blockIdx.x >> 3;  // 8 blocks per b (512/64)

  pcs[tid] = pc[(size_t)b * 512 + tid];
  pcs[tid + 256] = pc[(size_t)b * 512 + 256 + tid];

  // ---- stage hs -> rowbuf[row][512..768), bf16, swizzled ----
  {
    const float4* hsv = (const float4*)(hs + row0 * 128);
#pragma unroll
    for (int it = 0; it < 8; ++it) {
      int idx = it * 256 + tid;
      int r = idx >> 5, c4 = idx & 31;
      float4 v = hsv[idx];
      uint2 p;
      p.x = (uint_t)f2bf(v.x) | ((uint_t)f2bf(v.y) << 16);
      p.y = (uint_t)f2bf(v.z) | ((uint_t)f2bf(v.w) << 16);
      int byte = (r * 768 + 512 + c4 * 8) ^ ((r & 7) << 4);
      *(uint2*)(rowbuf + byte) = p;
    }
  }

  float wo[4];
#pragma unroll
  for (int i = 0; i < 4; ++i) wo[i] = Wo[(wv * 4 + i) * 16 + l4];

  // ---- pos A-frags in registers (k = hi4*8..hi4*8+7 of [c|sin|cos|pad]) ----
  bf16x8 Apos[4];
#pragma unroll
  for (int mt = 0; mt < 4; ++mt) {
    float c = coords[row0 + mt * 16 + l4];
    float pv[8];
    if (hi4 == 0) {
      pv[0] = c;
#pragma unroll
      for (int f = 0; f < 7; ++f) pv[1 + f] = __sinf(1.25f * f * c);
    } else if (hi4 == 1) {
      pv[0] = __sinf(8.75f * c);
#pragma unroll
      for (int f = 0; f < 7; ++f) pv[1 + f] = __cosf(1.25f * f * c);
    } else if (hi4 == 2) {
      pv[0] = __cosf(8.75f * c);
#pragma unroll
      for (int f = 0; f < 7; ++f) pv[1 + f] = 0.0f;
    } else {
#pragma unroll
      for (int j = 0; j < 8; ++j) pv[j] = 0.0f;
    }
    bf16x8 a;
#pragma unroll
    for (int j = 0; j < 8; ++j) a[j] = (__bf16)pv[j];
    Apos[mt] = a;
  }

  __syncthreads();

  f32x4 acc[4][4];
#pragma unroll
  for (int mt = 0; mt < 4; ++mt)
#pragma unroll
    for (int i = 0; i < 4; ++i) acc[mt][i] = (f32x4){0.f, 0.f, 0.f, 0.f};

  // ---------------- GEMM0: K=160 (5 k32-steps: pos, then hs) ----------------
  {
    const uint4* Bbase = (const uint4*)WT0p;
    bf16x8 Bf[2][4], Acur[4], Anxt[4];
#pragma unroll
    for (int i = 0; i < 4; ++i)
      Bf[0][i] = __builtin_bit_cast(bf16x8, Bbase[(0 * 16 + wv * 4 + i) * 64 + l]);
#pragma unroll
    for (int mt = 0; mt < 4; ++mt) Acur[mt] = Apos[mt];

#pragma unroll
    for (int ks = 0; ks < 5; ++ks) {
      const int cur = ks & 1;
      if (ks < 4) {
#pragma unroll
        for (int i = 0; i < 4; ++i)
          Bf[cur ^ 1][i] = __builtin_bit_cast(bf16x8, Bbase[((ks + 1) * 16 + wv * 4 + i) * 64 + l]);
#pragma unroll
        for (int mt = 0; mt < 4; ++mt) {
          int row = mt * 16 + l4;
          int byte = (row * 768 + 512 + ks * 64 + hi4 * 16) ^ ((row & 7) << 4);
          bf16x8 a;
          __builtin_memcpy(&a, rowbuf + byte, 16);
          Anxt[mt] = a;
        }
      }
#pragma unroll
      for (int mt = 0; mt < 4; ++mt)
#pragma unroll
        for (int i = 0; i < 4; ++i)
          acc[mt][i] = __builtin_amdgcn_mfma_f32_16x16x32_bf16(Acur[mt], Bf[cur][i], acc[mt][i], 0, 0, 0);
#pragma unroll
      for (int mt = 0; mt < 4; ++mt) Acur[mt] = Anxt[mt];
    }
  }

  // ---- epilogue0: relu(acc + pc0) -> x0 (bf16, swizzled) in rowbuf[row][0..512) ----
#pragma unroll
  for (int mt = 0; mt < 4; ++mt)
#pragma unroll
    for (int i = 0; i < 4; ++i) {
      int n = (wv * 4 + i) * 16 + l4;
#pragma unroll
      for (int r = 0; r < 4; ++r) {
        int row = mt * 16 + hi4 * 4 + r;
        float v = fmaxf(acc[mt][i][r] + pcs[n], 0.0f);
        int byte = (row * 768 + n * 2) ^ ((row & 7) << 4);
        *(ushort_t*)(rowbuf + byte) = f2bf(v);
      }
    }
  __syncthreads();

#pragma unroll
  for (int mt = 0; mt < 4; ++mt)
#pragma unroll
    for (int i = 0; i < 4; ++i) acc[mt][i] = (f32x4){0.f, 0.f, 0.f, 0.f};

  // ---------------- GEMM1: K=384 (12 k32-steps: x0 cols 0..255, hs 256..383) ----------------
  {
    const uint4* Bbase = (const uint4*)WT1p;
    bf16x8 Bf[2][4], Acur[4], Anxt[4];
#pragma unroll
    for (int i = 0; i < 4; ++i)
      Bf[0][i] = __builtin_bit_cast(bf16x8, Bbase[(0 * 16 + wv * 4 + i) * 64 + l]);
#pragma unroll
    for (int mt = 0; mt < 4; ++mt) {
      int row = mt * 16 + l4;
      int byte = (row * 768 + hi4 * 16) ^ ((row & 7) << 4);
      bf16x8 a;
      __builtin_memcpy(&a, rowbuf + byte, 16);
      Acur[mt] = a;
    }
#pragma unroll
    for (int ks = 0; ks < 12; ++ks) {
      const int cur = ks & 1;
      if (ks < 11) {
#pragma unroll
        for (int i = 0; i < 4; ++i)
          Bf[cur ^ 1][i] = __builtin_bit_cast(bf16x8, Bbase[((ks + 1) * 16 + wv * 4 + i) * 64 + l]);
#pragma unroll
        for (int mt = 0; mt < 4; ++mt) {
          int row = mt * 16 + l4;
          int byte = (row * 768 + (ks + 1) * 64 + hi4 * 16) ^ ((row & 7) << 4);
          bf16x8 a;
          __builtin_memcpy(&a, rowbuf + byte, 16);
          Anxt[mt] = a;
        }
      }
#pragma unroll
      for (int mt = 0; mt < 4; ++mt)
#pragma unroll
        for (int i = 0; i < 4; ++i)
          acc[mt][i] = __builtin_amdgcn_mfma_f32_16x16x32_bf16(Acur[mt], Bf[cur][i], acc[mt][i], 0, 0, 0);
#pragma unroll
      for (int mt = 0; mt < 4; ++mt) Acur[mt] = Anxt[mt];
    }
  }

  // ---- epilogue1: relu(acc + pc1) . Wo, 16-lane butterfly reduce, psum ----
#pragma unroll
  for (int mt = 0; mt < 4; ++mt) {
#pragma unroll
    for (int r = 0; r < 4; ++r) {
      float s = 0.0f;
#pragma unroll
      for (int i = 0; i < 4; ++i) {
        int n = (wv * 4 + i) * 16 + l4;
        s += fmaxf(acc[mt][i][r] + pcs[256 + n], 0.0f) * wo[i];
      }
      s += __shfl_xor(s, 1);
      s += __shfl_xor(s, 2);
      s += __shfl_xor(s, 4);
      s += __shfl_xor(s, 8);
      if (l4 == 0) psum[wv][mt * 16 + hi4 * 4 + r] = s;
    }
  }
  __syncthreads();
  if (tid < 64)
    out[row0 + tid] = bo[0] + psum[0][tid] + psum[1][tid] + psum[2][tid] + psum[3][tid];
}

extern "C" void kernel_launch(void* const* d_in, const int* in_sizes, int n_in,
                              void* d_out, int out_size, void* d_ws, size_t ws_size,
                              hipStream_t stream) {
  (void)in_sizes; (void)n_in; (void)out_size; (void)ws_size;
  const float* coords    = (const float*)d_in[0];
  const float* code      = (const float*)d_in[1];
  const float* hs        = (const float*)d_in[2];
  const float* x_statics = (const float*)d_in[3];
  const int*   dir_idx   = (const int*)d_in[4];
  const float* W_mod     = (const float*)d_in[5];
  const float* b_mod     = (const float*)d_in[6];
  const float* W0        = (const float*)d_in[7];
  const float* b0        = (const float*)d_in[8];
  const float* W1        = (const float*)d_in[9];
  const float* b1        = (const float*)d_in[10];
  const float* Wo        = (const float*)d_in[11];
  const float* bo        = (const float*)d_in[12];
  const float* Bmat      = (const float*)d_in[13];
  const float* Ws1       = (const float*)d_in[14];
  const float* bs1       = (const float*)d_in[15];
  const float* Ws2       = (const float*)d_in[16];
  const float* bs2       = (const float*)d_in[17];
  const float* dir_emb   = (const float*)d_in[18];
  float* out = (float*)d_out;
  float* wsf = (float*)d_ws;

  float*    WmT  = wsf + WMT_OFF;
  float*    pc   = wsf + PC_OFF;
  ushort_t* WT0p = (ushort_t*)(wsf + WT0P_OFF);
  ushort_t* WT1p = (ushort_t*)(wsf + WT1P_OFF);

  hipLaunchKernelGGL(pack_mfma_k, dim3(1024), dim3(256), 0, stream,
                     W0, W1, W_mod, WmT, WT0p, WT1p);
  hipLaunchKernelGGL(precompute_pc_k, dim3(1024), dim3(512), 0, stream,
                     code, x_statics, dir_idx, WmT, b_mod, b0, b1,
                     Bmat, Ws1, bs1, Ws2, bs2, dir_emb, pc);
  hipLaunchKernelGGL(film_mfma, dim3(8192), dim3(256), 0, stream,
                     coords, hs, pc, WT0p, WT1p, Wo, bo, out);
}